// Round 17
// baseline (166.789 us; speedup 1.0000x reference)
//
#include <hip/hip_runtime.h>
#include <hip/hip_bf16.h>

// Oja scan, reformulated. G[b][n][t] = row_n . x_t ; S = X X^T.
// Scan: u[j]=W_t.x_j :  y_t = sigmoid(u[t]); u <- (1-lr*y^2)u + (lr*y)S[t,:]
// R17: FULL FUSION. One kernel, 544 blocks (68 nt x 8 b), all co-resident
// (38.4 KB LDS -> 4 blk/CU; bounds(256,4) -> <=128 VGPR -> 16 waves/CU).
// Block nt<64: issue cold W-panel loads first, do 1/512 of X->bf16 cvt,
// flag; wait xflag; B-frags in regs; 2-half LDS stage + 32 MFMA; G-tile
// kept in LDS; wait sflag[b]; run R10 scan with own tile as u-init.
// Block nt>=64: same gemm on X rows -> S[b] tile to ws -> fence+flag.
// Flags zeroed by 64-B hipMemsetAsync each call (graph-safe).

#define BB 8
#define TT 64
#define NI 1024
#define NO 1024

typedef __attribute__((ext_vector_type(8))) short bf16x8;
typedef __attribute__((ext_vector_type(4))) float f32x4;
typedef __attribute__((ext_vector_type(4))) float f32x4v;

__device__ __forceinline__ short f2bf(float f) {
    __hip_bfloat16 h = __float2bfloat16(f);
    return __builtin_bit_cast(short, h);
}

__global__ __launch_bounds__(256, 4)
void fused_kernel(const float* __restrict__ X, const float* __restrict__ W0,
                  ushort* __restrict__ Xb16, float* __restrict__ Sws,
                  int* __restrict__ flags, float* __restrict__ out)
{
    __shared__ __align__(16) ushort As[16][520];    // 16,640 B (one K-half)
    __shared__ __align__(16) float  Gtile[16][68];  //  4,352 B
    __shared__ __align__(16) float  Sl[64][68];     // 17,408 B

    const int tid  = threadIdx.x;
    const int lane = tid & 63;
    const int wave = tid >> 6;
    const int b  = blockIdx.x & 7;
    const int nt = blockIdx.x >> 3;        // 0..67
    const bool isS = (nt >= 64);
    const int t0 = wave * 16;
    const int r  = lane & 15;
    const int kb = lane >> 4;

    int* xflag = flags;                    // [0]
    int* sflag = flags + 8;                // [8..15]

    // ---- issue A half-0 loads FIRST (the critical cold W stream) ----
    const int j = tid >> 4;                // panel row 0..15
    const int x = tid & 15;
    const float* __restrict__ Abase = isS
        ? (X  + ((size_t)b * TT + (nt - 64) * 16 + j) * NI)
        : (W0 + ((size_t)b * NO + nt * 16 + j) * NI);

    f32x4v v[8];
#pragma unroll
    for (int q = 0; q < 8; ++q)
        v[q] = __builtin_nontemporal_load(
            reinterpret_cast<const f32x4v*>(Abase + q * 64 + x * 4));

    // ---- X-cvt share: blocks 0..511 (nt<64) convert 1024 f32 each ----
    if (!isS) {
        const size_t base = (size_t)blockIdx.x * 1024 + (size_t)tid * 4;
        const float4 xv = *reinterpret_cast<const float4*>(X + base);
        short4 s4;
        s4.x = f2bf(xv.x); s4.y = f2bf(xv.y); s4.z = f2bf(xv.z); s4.w = f2bf(xv.w);
        *reinterpret_cast<short4*>(Xb16 + base) = s4;
        __threadfence();
        __syncthreads();                   // all stores + fences done
        if (tid == 0) atomicAdd(xflag, 1);
    }

    // ---- wait until all of Xb16 is published, then load B-frags ----
    if (tid == 0) {
        while (__hip_atomic_load(xflag, __ATOMIC_RELAXED,
                                 __HIP_MEMORY_SCOPE_AGENT) < 512)
            __builtin_amdgcn_s_sleep(2);
    }
    __syncthreads();
    __threadfence();                       // acquire before reading Xb16

    bf16x8 breg[32];
    {
        const ushort* __restrict__ Bb =
            Xb16 + ((size_t)b * TT + t0 + r) * NI + kb * 8;
#pragma unroll
        for (int kk = 0; kk < 32; ++kk)
            breg[kk] = *reinterpret_cast<const bf16x8*>(Bb + kk * 32);
    }

    // ---- stage half0 (cvt + ds_write) ----
#pragma unroll
    for (int q = 0; q < 8; ++q) {
        short4 s4;
        s4.x = f2bf(v[q][0]); s4.y = f2bf(v[q][1]);
        s4.z = f2bf(v[q][2]); s4.w = f2bf(v[q][3]);
        *reinterpret_cast<short4*>(&As[j][q * 64 + x * 4]) = s4;
    }
    __syncthreads();

    // issue half-1 loads (fly during half-0 MFMA)
#pragma unroll
    for (int q = 0; q < 8; ++q)
        v[q] = __builtin_nontemporal_load(
            reinterpret_cast<const f32x4v*>(Abase + 512 + q * 64 + x * 4));

    // ---- MFMA half0 ----
    f32x4 acc = {0.f, 0.f, 0.f, 0.f};
    const ushort* __restrict__ Ap = &As[r][kb * 8];
#pragma unroll
    for (int kk = 0; kk < 16; ++kk) {
        const bf16x8 a = *reinterpret_cast<const bf16x8*>(Ap + kk * 32);
        acc = __builtin_amdgcn_mfma_f32_16x16x32_bf16(a, breg[kk], acc, 0, 0, 0);
    }
    __syncthreads();                       // everyone done reading half0

    // ---- stage half1 ----
#pragma unroll
    for (int q = 0; q < 8; ++q) {
        short4 s4;
        s4.x = f2bf(v[q][0]); s4.y = f2bf(v[q][1]);
        s4.z = f2bf(v[q][2]); s4.w = f2bf(v[q][3]);
        *reinterpret_cast<short4*>(&As[j][q * 64 + x * 4]) = s4;
    }
    __syncthreads();

    // ---- MFMA half1 ----
#pragma unroll
    for (int kk = 0; kk < 16; ++kk) {
        const bf16x8 a = *reinterpret_cast<const bf16x8*>(Ap + kk * 32);
        acc = __builtin_amdgcn_mfma_f32_16x16x32_bf16(a, breg[16 + kk], acc, 0, 0, 0);
    }

    // ---- acc -> Gtile (D layout: col t = lane&15, row n = (lane>>4)*4+rr) ----
    const int tcol = lane & 15;
    const int mrow = (lane >> 4) * 4;
#pragma unroll
    for (int rr = 0; rr < 4; ++rr)
        Gtile[mrow + rr][t0 + tcol] = acc[rr];
    __syncthreads();

    if (isS) {
        // publish S-tile: coalesced copy Gtile -> Sws[b]
        const float4 gv = *reinterpret_cast<const float4*>(&Gtile[j][x * 4]);
        *reinterpret_cast<float4*>(
            &Sws[((size_t)b * 64 + (nt - 64) * 16 + j) * 64 + x * 4]) = gv;
        __threadfence();
        __syncthreads();
        if (tid == 0) atomicAdd(&sflag[b], 1);
        return;
    }

    // ---- scan: wait for S[b] (4 producer tiles) ----
    if (tid == 0) {
        while (__hip_atomic_load(&sflag[b], __ATOMIC_RELAXED,
                                 __HIP_MEMORY_SCOPE_AGENT) < 4)
            __builtin_amdgcn_s_sleep(2);
    }
    __syncthreads();
    __threadfence();                       // acquire before reading Sws

    // stage Sl[64][68] from Sws[b] (4096 f32)
    {
        const float* __restrict__ Sb = Sws + (size_t)b * 4096;
#pragma unroll
        for (int q = 0; q < 4; ++q) {
            const int idx  = tid + q * 256;   // float4 index 0..1023
            const int srow = idx >> 4;
            const int sx   = idx & 15;
            *reinterpret_cast<float4*>(&Sl[srow][sx * 4]) =
                *reinterpret_cast<const float4*>(Sb + srow * 64 + sx * 4);
        }
    }

    // u-init from OWN Gtile (rows o0..o0+15 are exactly this block's tile)
    const int r2 = lane & 3;
    const int jb = lane >> 2;
    const float4 uu = *reinterpret_cast<const float4*>(&Gtile[wave * 4 + r2][jb * 4]);
    float u0 = uu.x, u1 = uu.y, u2 = uu.z, u3 = uu.w;
    __syncthreads();                       // Sl staged

    const float lr   = 1.0f / 1024.0f;
    const float nL2E = -1.44269504f;
    float y0 = 0.f, y1 = 0.f, y2 = 0.f, y3 = 0.f;

#pragma unroll
    for (int t = 0; t < TT; ++t) {
        const int srcl = (t & 0x3C) | r2;
        const float uv = ((t & 3) == 0) ? u0 : ((t & 3) == 1) ? u1
                       : ((t & 3) == 2) ? u2 : u3;
        const float pre = __shfl(uv, srcl, 64);

        const float e = __builtin_amdgcn_exp2f(pre * nL2E);
        const float y = __builtin_amdgcn_rcpf(1.0f + e);

        const bool own = (jb == (t >> 2));
        if ((t & 3) == 0) y0 = own ? y : y0;
        if ((t & 3) == 1) y1 = own ? y : y1;
        if ((t & 3) == 2) y2 = own ? y : y2;
        if ((t & 3) == 3) y3 = own ? y : y3;

        const float c2 = lr * y;
        const float c1 = fmaf(-c2, y, 1.0f);

        const float4 s = *reinterpret_cast<const float4*>(&Sl[t][jb * 4]);
        u0 = fmaf(c1, u0, c2 * s.x);
        u1 = fmaf(c1, u1, c2 * s.y);
        u2 = fmaf(c1, u2, c2 * s.z);
        u3 = fmaf(c1, u3, c2 * s.w);
    }

    // y bounce via LDS (overlay on As; 272-B row stride keeps 16-B alignment)
    float (*ybuf)[68] = reinterpret_cast<float (*)[68]>(&As[0][0]);
    {
        float4 yv; yv.x = y0; yv.y = y1; yv.z = y2; yv.w = y3;
        *reinterpret_cast<float4*>(&ybuf[wave * 4 + r2][jb * 4]) = yv;
    }
    __syncthreads();

    {
        const int o0 = nt * 16;
        const int t  = tid >> 2;
        const int g  = tid & 3;
        float4 ov;
        ov.x = ybuf[g * 4 + 0][t];
        ov.y = ybuf[g * 4 + 1][t];
        ov.z = ybuf[g * 4 + 2][t];
        ov.w = ybuf[g * 4 + 3][t];
        *reinterpret_cast<float4*>(
            &out[(size_t)b * TT * NO + (size_t)t * NO + o0 + g * 4]) = ov;
    }
}

extern "C" void kernel_launch(void* const* d_in, const int* in_sizes, int n_in,
                              void* d_out, int out_size, void* d_ws, size_t ws_size,
                              hipStream_t stream) {
    const float* X  = (const float*)d_in[0];   // [8][64][1024]
    const float* W0 = (const float*)d_in[1];   // [8][1024][1024]
    float* out = (float*)d_out;                // [8][64][1024]

    int*    flags = (int*)d_ws;                           // 64 B (16 ints)
    float*  Sws   = (float*)((char*)d_ws + 256);          // 8*64*64 f32 = 131,072 B
    ushort* Xb16  = (ushort*)((char*)d_ws + 131328);      // 1,048,576 B

    hipMemsetAsync(flags, 0, 64, stream);                 // zero flags every call
    fused_kernel<<<544, 256, 0, stream>>>(X, W0, Xb16, Sws, flags, out);
}

// Round 19
// 33.581 us; speedup vs baseline: 4.9668x; 4.9668x over previous
//
#include <hip/hip_runtime.h>
#include <hip/hip_bf16.h>

// Oja scan, reformulated. G[b][n][t] = row_n . x_t ; S = X X^T.
// Scan: u[j]=W_t.x_j :  y_t = sigmoid(u[t]); u <- (1-lr*y^2)u + (lr*y)S[t,:]
// R19 = R18 with the S-stage coverage bug fixed (each thread moves 32
// shorts, 4x bf16x8, not 2x — half of every S tile was stale W data).
// Structure: xcvt (X->bf16), then fused gemm+redundant-S+scan, no
// cross-block sync (R17's fences/spins were the pathology).

#define BB 8
#define TT 64
#define NI 1024
#define NO 1024

typedef __attribute__((ext_vector_type(8))) short bf16x8;
typedef __attribute__((ext_vector_type(4))) float f32x4;

__device__ __forceinline__ short f2bf(float f) {
    __hip_bfloat16 h = __float2bfloat16(f);
    return __builtin_bit_cast(short, h);
}

// ---------- Kernel 0: X (f32, 524288 elems) -> bf16 ----------
__global__ __launch_bounds__(256)
void xcvt_kernel(const float* __restrict__ X, ushort* __restrict__ Xb16)
{
    const int i = blockIdx.x * 256 + threadIdx.x;   // float4 index, 131072 total
    const float4 v = *reinterpret_cast<const float4*>(X + (size_t)i * 4);
    short4 s;
    s.x = f2bf(v.x); s.y = f2bf(v.y); s.z = f2bf(v.z); s.w = f2bf(v.w);
    *reinterpret_cast<short4*>(Xb16 + (size_t)i * 4) = s;
}

// ---------- Kernel 1: fused gemm + redundant-S + scan ----------
// Grid 512: b = bid&7, nt = bid>>3 (0..63). 256 thr = 4 waves.
__global__ __launch_bounds__(256, 2)
void fused_kernel(const float* __restrict__ W0, const ushort* __restrict__ Xb16,
                  float* __restrict__ out)
{
    __shared__ __align__(16) ushort As[16][520];    // 16,640 B (one K-half)
    __shared__ __align__(16) float  Gtile[16][68];  //  4,352 B
    __shared__ __align__(16) float  Sl[64][68];     // 17,408 B

    const int tid  = threadIdx.x;
    const int lane = tid & 63;
    const int wave = tid >> 6;
    const int b  = blockIdx.x & 7;
    const int nt = blockIdx.x >> 3;        // 0..63
    const int t0 = wave * 16;
    const int r  = lane & 15;
    const int kb = lane >> 4;
    const int j  = tid >> 4;               // stage row 0..15
    const int x  = tid & 15;

    // ---- issue W half-0 loads FIRST (the cold stream) ----
    const float* __restrict__ Wrow = W0 + ((size_t)b * NO + nt * 16 + j) * NI;
    float4 v[8];
#pragma unroll
    for (int q = 0; q < 8; ++q)
        v[q] = *reinterpret_cast<const float4*>(Wrow + q * 64 + x * 4);

    // ---- B-frags from Xb16 (L2/L3-hot; 32 x 16B per thread) ----
    bf16x8 breg[32];
    {
        const ushort* __restrict__ Bb =
            Xb16 + ((size_t)b * TT + t0 + r) * NI + kb * 8;
#pragma unroll
        for (int kk = 0; kk < 32; ++kk)
            breg[kk] = *reinterpret_cast<const bf16x8*>(Bb + kk * 32);
    }

    // ---- stage W half0 ----
#pragma unroll
    for (int q = 0; q < 8; ++q) {
        short4 s4;
        s4.x = f2bf(v[q].x); s4.y = f2bf(v[q].y);
        s4.z = f2bf(v[q].z); s4.w = f2bf(v[q].w);
        *reinterpret_cast<short4*>(&As[j][q * 64 + x * 4]) = s4;
    }
    __syncthreads();

    // issue W half-1 loads (fly during half-0 MFMA)
#pragma unroll
    for (int q = 0; q < 8; ++q)
        v[q] = *reinterpret_cast<const float4*>(Wrow + 512 + q * 64 + x * 4);

    // ---- G MFMA half0 ----
    f32x4 acc = {0.f, 0.f, 0.f, 0.f};
    const ushort* __restrict__ Ap = &As[r][kb * 8];
#pragma unroll
    for (int kk = 0; kk < 16; ++kk) {
        const bf16x8 a = *reinterpret_cast<const bf16x8*>(Ap + kk * 32);
        acc = __builtin_amdgcn_mfma_f32_16x16x32_bf16(a, breg[kk], acc, 0, 0, 0);
    }
    __syncthreads();

    // ---- stage W half1 ----
#pragma unroll
    for (int q = 0; q < 8; ++q) {
        short4 s4;
        s4.x = f2bf(v[q].x); s4.y = f2bf(v[q].y);
        s4.z = f2bf(v[q].z); s4.w = f2bf(v[q].w);
        *reinterpret_cast<short4*>(&As[j][q * 64 + x * 4]) = s4;
    }
    __syncthreads();

    // ---- G MFMA half1 ----
#pragma unroll
    for (int kk = 0; kk < 16; ++kk) {
        const bf16x8 a = *reinterpret_cast<const bf16x8*>(Ap + kk * 32);
        acc = __builtin_amdgcn_mfma_f32_16x16x32_bf16(a, breg[16 + kk], acc, 0, 0, 0);
    }

    // acc -> Gtile (D layout: col t = lane&15, row n = (lane>>4)*4+rr) [m89]
    const int tcol = lane & 15;
    const int mrow = (lane >> 4) * 4;
#pragma unroll
    for (int rr = 0; rr < 4; ++rr)
        Gtile[mrow + rr][t0 + tcol] = acc[rr];
    __syncthreads();   // G MFMA done reading As; Gtile published

    // ---- redundant S[b]: 4 s-chunks x 2 K-halves from Xb16 ----
#pragma unroll 1
    for (int c = 0; c < 4; ++c) {
        f32x4 sacc = {0.f, 0.f, 0.f, 0.f};
#pragma unroll
        for (int h = 0; h < 2; ++h) {
            // stage 16 X rows (c*16+j), cols h*512..+512 (32 shorts = 64 B/thread)
            const ushort* src =
                Xb16 + ((size_t)b * TT + c * 16 + j) * NI + h * 512 + x * 32;
            *reinterpret_cast<bf16x8*>(&As[j][x * 32])      =
                *reinterpret_cast<const bf16x8*>(src);
            *reinterpret_cast<bf16x8*>(&As[j][x * 32 + 8])  =
                *reinterpret_cast<const bf16x8*>(src + 8);
            *reinterpret_cast<bf16x8*>(&As[j][x * 32 + 16]) =
                *reinterpret_cast<const bf16x8*>(src + 16);
            *reinterpret_cast<bf16x8*>(&As[j][x * 32 + 24]) =
                *reinterpret_cast<const bf16x8*>(src + 24);
            __syncthreads();
#pragma unroll
            for (int kk = 0; kk < 16; ++kk) {
                const bf16x8 a = *reinterpret_cast<const bf16x8*>(Ap + kk * 32);
                sacc = __builtin_amdgcn_mfma_f32_16x16x32_bf16(a, breg[h * 16 + kk],
                                                               sacc, 0, 0, 0);
            }
            __syncthreads();   // done reading As before next stage
        }
#pragma unroll
        for (int rr = 0; rr < 4; ++rr)
            Sl[c * 16 + mrow + rr][t0 + tcol] = sacc[rr];
    }
    __syncthreads();   // Sl complete

    // ---- R10 lane-parallel scan; u-init from OWN Gtile ----
    const int r2 = lane & 3;
    const int jb = lane >> 2;
    const float4 uu = *reinterpret_cast<const float4*>(&Gtile[wave * 4 + r2][jb * 4]);
    float u0 = uu.x, u1 = uu.y, u2 = uu.z, u3 = uu.w;

    const float lr   = 1.0f / 1024.0f;
    const float nL2E = -1.44269504f;
    float y0 = 0.f, y1 = 0.f, y2 = 0.f, y3 = 0.f;

#pragma unroll
    for (int t = 0; t < TT; ++t) {
        const int srcl = (t & 0x3C) | r2;
        const float uv = ((t & 3) == 0) ? u0 : ((t & 3) == 1) ? u1
                       : ((t & 3) == 2) ? u2 : u3;
        const float pre = __shfl(uv, srcl, 64);

        const float e = __builtin_amdgcn_exp2f(pre * nL2E);
        const float y = __builtin_amdgcn_rcpf(1.0f + e);

        const bool own = (jb == (t >> 2));
        if ((t & 3) == 0) y0 = own ? y : y0;
        if ((t & 3) == 1) y1 = own ? y : y1;
        if ((t & 3) == 2) y2 = own ? y : y2;
        if ((t & 3) == 3) y3 = own ? y : y3;

        const float c2 = lr * y;
        const float c1 = fmaf(-c2, y, 1.0f);

        const float4 s = *reinterpret_cast<const float4*>(&Sl[t][jb * 4]);
        u0 = fmaf(c1, u0, c2 * s.x);
        u1 = fmaf(c1, u1, c2 * s.y);
        u2 = fmaf(c1, u2, c2 * s.z);
        u3 = fmaf(c1, u3, c2 * s.w);
    }

    // y bounce via LDS (overlay on As; rows 272 B apart, 16-B aligned)
    float (*ybuf)[68] = reinterpret_cast<float (*)[68]>(&As[0][0]);
    {
        float4 yv; yv.x = y0; yv.y = y1; yv.z = y2; yv.w = y3;
        *reinterpret_cast<float4*>(&ybuf[wave * 4 + r2][jb * 4]) = yv;
    }
    __syncthreads();

    {
        const int o0 = nt * 16;
        const int t  = tid >> 2;
        const int g  = tid & 3;
        float4 ov;
        ov.x = ybuf[g * 4 + 0][t];
        ov.y = ybuf[g * 4 + 1][t];
        ov.z = ybuf[g * 4 + 2][t];
        ov.w = ybuf[g * 4 + 3][t];
        *reinterpret_cast<float4*>(
            &out[(size_t)b * TT * NO + (size_t)t * NO + o0 + g * 4]) = ov;
    }
}

extern "C" void kernel_launch(void* const* d_in, const int* in_sizes, int n_in,
                              void* d_out, int out_size, void* d_ws, size_t ws_size,
                              hipStream_t stream) {
    const float* X  = (const float*)d_in[0];   // [8][64][1024]
    const float* W0 = (const float*)d_in[1];   // [8][1024][1024]
    float* out = (float*)d_out;                // [8][64][1024]

    ushort* Xb16 = (ushort*)d_ws;              // 1,048,576 B

    xcvt_kernel<<<512, 256, 0, stream>>>(X, Xb16);
    fused_kernel<<<512, 256, 0, stream>>>(W0, Xb16, out);
}

// Round 20
// 31.880 us; speedup vs baseline: 5.2317x; 1.0533x over previous
//
#include <hip/hip_runtime.h>
#include <hip/hip_bf16.h>

// Oja scan, reformulated. G[b][n][t] = row_n . x_t ; S = X X^T.
// Scan: u[j]=W_t.x_j : y_t = sigmoid(u[t]); u <- (1-lr*y^2)u + (lr*y)S[t,:]
// R20: fusion with S hoisted out of the tail (R19's redundant per-block
// S-phase was +8us at 2 blocks/CU).
//  k0 prep (544 blk): 0..511 xcvt share; 512..543 S-gram via MFMA with
//     operands cvt'd directly from f32 X (no intra-kernel deps) -> Sws.
//  k1 fused (512 blk): W 2-half LDS stage + 32 MFMA -> Gtile (overlaid on
//     As), Sl one-shot from L2-hot Sws, R10 lane-parallel scan -> out.
// Kernel boundary = the only global barrier (R17 lesson: no flags/fences).

#define BB 8
#define TT 64
#define NI 1024
#define NO 1024

typedef __attribute__((ext_vector_type(8))) short bf16x8;
typedef __attribute__((ext_vector_type(4))) float f32x4;

__device__ __forceinline__ short f2bf(float f) {
    __hip_bfloat16 h = __float2bfloat16(f);
    return __builtin_bit_cast(short, h);
}

// ---------- Kernel 0: prep = xcvt (blocks 0..511) + S-gram (512..543) ----
__global__ __launch_bounds__(256, 2)
void prep_kernel(const float* __restrict__ X, ushort* __restrict__ Xb16,
                 float* __restrict__ Sws)
{
    __shared__ __align__(16) ushort As[16][520];   // used by S-gram blocks only

    const int tid = threadIdx.x;
    if (blockIdx.x < 512) {
        // ---- xcvt share: 1024 floats per block ----
        const int i = blockIdx.x * 256 + tid;
        const float4 v = *reinterpret_cast<const float4*>(X + (size_t)i * 4);
        short4 s;
        s.x = f2bf(v.x); s.y = f2bf(v.y); s.z = f2bf(v.z); s.w = f2bf(v.w);
        *reinterpret_cast<short4*>(Xb16 + (size_t)i * 4) = s;
        return;
    }

    // ---- S-gram: block (b, c) computes S[b] rows c*16..+16 (K=1024) ----
    const int id   = blockIdx.x - 512;   // 0..31
    const int b    = id & 7;
    const int c    = id >> 3;            // 0..3
    const int lane = tid & 63;
    const int wave = tid >> 6;
    const int t0 = wave * 16;
    const int r  = lane & 15;
    const int kb = lane >> 4;
    const int j  = tid >> 4;
    const int x  = tid & 15;

    // B-frags: X[b] rows t0+r, cvt f32->bf16 into regs
    bf16x8 breg[32];
    {
        const float* __restrict__ Bb = X + ((size_t)b * TT + t0 + r) * NI + kb * 8;
#pragma unroll
        for (int kk = 0; kk < 32; ++kk) {
            const float4 lo = *reinterpret_cast<const float4*>(Bb + kk * 32);
            const float4 hi = *reinterpret_cast<const float4*>(Bb + kk * 32 + 4);
            bf16x8 f;
            f[0] = f2bf(lo.x); f[1] = f2bf(lo.y); f[2] = f2bf(lo.z); f[3] = f2bf(lo.w);
            f[4] = f2bf(hi.x); f[5] = f2bf(hi.y); f[6] = f2bf(hi.z); f[7] = f2bf(hi.w);
            breg[kk] = f;
        }
    }

    const float* __restrict__ Arow = X + ((size_t)b * TT + c * 16 + j) * NI;
    f32x4 sacc = {0.f, 0.f, 0.f, 0.f};
    const ushort* __restrict__ Ap = &As[r][kb * 8];
#pragma unroll
    for (int h = 0; h < 2; ++h) {
        float4 v[8];
#pragma unroll
        for (int q = 0; q < 8; ++q)
            v[q] = *reinterpret_cast<const float4*>(Arow + h * 512 + q * 64 + x * 4);
#pragma unroll
        for (int q = 0; q < 8; ++q) {
            short4 s4;
            s4.x = f2bf(v[q].x); s4.y = f2bf(v[q].y);
            s4.z = f2bf(v[q].z); s4.w = f2bf(v[q].w);
            *reinterpret_cast<short4*>(&As[j][q * 64 + x * 4]) = s4;
        }
        __syncthreads();
#pragma unroll
        for (int kk = 0; kk < 16; ++kk) {
            const bf16x8 a = *reinterpret_cast<const bf16x8*>(Ap + kk * 32);
            sacc = __builtin_amdgcn_mfma_f32_16x16x32_bf16(a, breg[h * 16 + kk],
                                                           sacc, 0, 0, 0);
        }
        __syncthreads();
    }

    // D layout: col t = lane&15, row s = (lane>>4)*4 + rr   [m89-verified]
    const int tcol = lane & 15;
    const int mrow = (lane >> 4) * 4;
#pragma unroll
    for (int rr = 0; rr < 4; ++rr)
        Sws[((size_t)b * 64 + c * 16 + mrow + rr) * 64 + t0 + tcol] = sacc[rr];
}

// ---------- Kernel 1: fused gemm + scan ----------
// Grid 512: b = bid&7, nt = bid>>3. 256 thr = 4 waves.
__global__ __launch_bounds__(256, 2)
void fused_kernel(const float* __restrict__ W0, const ushort* __restrict__ Xb16,
                  const float* __restrict__ Sws, float* __restrict__ out)
{
    __shared__ __align__(16) ushort As[16][520];   // 16,640 B; Gtile/ybuf overlay
    __shared__ __align__(16) float  Sl[64][68];    // 17,408 B

    const int tid  = threadIdx.x;
    const int lane = tid & 63;
    const int wave = tid >> 6;
    const int b  = blockIdx.x & 7;
    const int nt = blockIdx.x >> 3;        // 0..63
    const int t0 = wave * 16;
    const int r  = lane & 15;
    const int kb = lane >> 4;
    const int j  = tid >> 4;
    const int x  = tid & 15;

    // ---- issue W half-0 loads FIRST (the cold stream) ----
    const float* __restrict__ Wrow = W0 + ((size_t)b * NO + nt * 16 + j) * NI;
    float4 v[8];
#pragma unroll
    for (int q = 0; q < 8; ++q)
        v[q] = *reinterpret_cast<const float4*>(Wrow + q * 64 + x * 4);

    // ---- B-frags from Xb16 (L2-hot) ----
    bf16x8 breg[32];
    {
        const ushort* __restrict__ Bb =
            Xb16 + ((size_t)b * TT + t0 + r) * NI + kb * 8;
#pragma unroll
        for (int kk = 0; kk < 32; ++kk)
            breg[kk] = *reinterpret_cast<const bf16x8*>(Bb + kk * 32);
    }

    // ---- stage W half0 ----
#pragma unroll
    for (int q = 0; q < 8; ++q) {
        short4 s4;
        s4.x = f2bf(v[q].x); s4.y = f2bf(v[q].y);
        s4.z = f2bf(v[q].z); s4.w = f2bf(v[q].w);
        *reinterpret_cast<short4*>(&As[j][q * 64 + x * 4]) = s4;
    }
    __syncthreads();

    // issue W half-1 loads (fly during half-0 MFMA)
#pragma unroll
    for (int q = 0; q < 8; ++q)
        v[q] = *reinterpret_cast<const float4*>(Wrow + 512 + q * 64 + x * 4);

    // ---- G MFMA half0 ----
    f32x4 acc = {0.f, 0.f, 0.f, 0.f};
    const ushort* __restrict__ Ap = &As[r][kb * 8];
#pragma unroll
    for (int kk = 0; kk < 16; ++kk) {
        const bf16x8 a = *reinterpret_cast<const bf16x8*>(Ap + kk * 32);
        acc = __builtin_amdgcn_mfma_f32_16x16x32_bf16(a, breg[kk], acc, 0, 0, 0);
    }
    __syncthreads();

    // ---- stage W half1 ----
#pragma unroll
    for (int q = 0; q < 8; ++q) {
        short4 s4;
        s4.x = f2bf(v[q].x); s4.y = f2bf(v[q].y);
        s4.z = f2bf(v[q].z); s4.w = f2bf(v[q].w);
        *reinterpret_cast<short4*>(&As[j][q * 64 + x * 4]) = s4;
    }
    __syncthreads();

    // ---- G MFMA half1 ----
#pragma unroll
    for (int kk = 0; kk < 16; ++kk) {
        const bf16x8 a = *reinterpret_cast<const bf16x8*>(Ap + kk * 32);
        acc = __builtin_amdgcn_mfma_f32_16x16x32_bf16(a, breg[16 + kk], acc, 0, 0, 0);
    }
    __syncthreads();   // all As reads done -> safe to overlay Gtile

    // ---- acc -> Gtile (overlay on As) ----
    float (*Gtile)[68] = reinterpret_cast<float (*)[68]>(&As[0][0]);
    const int tcol = lane & 15;
    const int mrow = (lane >> 4) * 4;
#pragma unroll
    for (int rr = 0; rr < 4; ++rr)
        Gtile[mrow + rr][t0 + tcol] = acc[rr];
    __syncthreads();   // Gtile published

    // ---- stage Sl from Sws (one shot, L2-hot) ----
    {
        const float* __restrict__ Sb = Sws + (size_t)b * 4096;
#pragma unroll
        for (int q = 0; q < 4; ++q) {
            const int idx  = tid + q * 256;   // float4 index 0..1023
            const int srow = idx >> 4;
            const int sx   = idx & 15;
            *reinterpret_cast<float4*>(&Sl[srow][sx * 4]) =
                *reinterpret_cast<const float4*>(Sb + srow * 64 + sx * 4);
        }
    }

    // u-init from OWN Gtile
    const int r2 = lane & 3;
    const int jb = lane >> 2;
    const float4 uu = *reinterpret_cast<const float4*>(&Gtile[wave * 4 + r2][jb * 4]);
    float u0 = uu.x, u1 = uu.y, u2 = uu.z, u3 = uu.w;
    __syncthreads();   // Sl staged; all Gtile reads done

    const float lr   = 1.0f / 1024.0f;
    const float nL2E = -1.44269504f;
    float y0 = 0.f, y1 = 0.f, y2 = 0.f, y3 = 0.f;

#pragma unroll
    for (int t = 0; t < TT; ++t) {
        const int srcl = (t & 0x3C) | r2;
        const float uv = ((t & 3) == 0) ? u0 : ((t & 3) == 1) ? u1
                       : ((t & 3) == 2) ? u2 : u3;
        const float pre = __shfl(uv, srcl, 64);

        const float e = __builtin_amdgcn_exp2f(pre * nL2E);
        const float y = __builtin_amdgcn_rcpf(1.0f + e);

        const bool own = (jb == (t >> 2));
        if ((t & 3) == 0) y0 = own ? y : y0;
        if ((t & 3) == 1) y1 = own ? y : y1;
        if ((t & 3) == 2) y2 = own ? y : y2;
        if ((t & 3) == 3) y3 = own ? y : y3;

        const float c2 = lr * y;
        const float c1 = fmaf(-c2, y, 1.0f);

        const float4 s = *reinterpret_cast<const float4*>(&Sl[t][jb * 4]);
        u0 = fmaf(c1, u0, c2 * s.x);
        u1 = fmaf(c1, u1, c2 * s.y);
        u2 = fmaf(c1, u2, c2 * s.z);
        u3 = fmaf(c1, u3, c2 * s.w);
    }

    // y bounce via LDS (reuse Gtile region — all Gtile reads done pre-scan)
    float (*ybuf)[68] = Gtile;
    {
        float4 yv; yv.x = y0; yv.y = y1; yv.z = y2; yv.w = y3;
        *reinterpret_cast<float4*>(&ybuf[wave * 4 + r2][jb * 4]) = yv;
    }
    __syncthreads();

    {
        const int o0 = nt * 16;
        const int t  = tid >> 2;
        const int g  = tid & 3;
        float4 ov;
        ov.x = ybuf[g * 4 + 0][t];
        ov.y = ybuf[g * 4 + 1][t];
        ov.z = ybuf[g * 4 + 2][t];
        ov.w = ybuf[g * 4 + 3][t];
        *reinterpret_cast<float4*>(
            &out[(size_t)b * TT * NO + (size_t)t * NO + o0 + g * 4]) = ov;
    }
}

extern "C" void kernel_launch(void* const* d_in, const int* in_sizes, int n_in,
                              void* d_out, int out_size, void* d_ws, size_t ws_size,
                              hipStream_t stream) {
    const float* X  = (const float*)d_in[0];   // [8][64][1024]
    const float* W0 = (const float*)d_in[1];   // [8][1024][1024]
    float* out = (float*)d_out;                // [8][64][1024]

    float*  Sws  = (float*)d_ws;                       // 8*64*64 f32 = 131,072 B
    ushort* Xb16 = (ushort*)((char*)d_ws + 131072);    // 1,048,576 B

    prep_kernel<<<544, 256, 0, stream>>>(X, Xb16, Sws);
    fused_kernel<<<512, 256, 0, stream>>>(W0, Xb16, Sws, out);
}

// Round 21
// 30.470 us; speedup vs baseline: 5.4739x; 1.0463x over previous
//
#include <hip/hip_runtime.h>
#include <hip/hip_bf16.h>

// Oja scan, reformulated. G[b][n][t] = row_n . x_t for n in [0,1088):
// rows 0..1023 = W0 rows, rows 1024..1087 = X rows (=> S = X X^T).
// Scan: exact projected Oja recurrence on u[j] = W_t . x_j:
//   y_t = sigmoid(u[t]); u <- (1-lr*y^2)u + (lr*y)S[t,:]
// R21 = R13 (best, 30.2us) minus the xcvt kernel: B-fragments are loaded
// as f32 from X and converted in-register once per block (hidden under the
// W panel-0 cold-load latency, which is issued FIRST). 2 kernels, 1 gap,
// no Xb16 buffer. Gemm swizzle/layout byte-identical to verified R13.

#define BB 8
#define TT 64
#define NI 1024
#define NO 1024
#define NTOT 1088            // 1024 W rows + 64 X rows

typedef __attribute__((ext_vector_type(8))) short bf16x8;
typedef __attribute__((ext_vector_type(4))) float f32x4;

__device__ __forceinline__ short f2bf(float f) {
    __hip_bfloat16 h = __float2bfloat16(f);
    return __builtin_bit_cast(short, h);
}

// ---------- Kernel 1: G[b][n][t] via MFMA ----------
// Grid 272 = 34 slots x 8 batches (b = blockIdx&7). Block: 256 thr, 4 waves;
// wave w owns t-tile w for BOTH panels nt = slot*2, slot*2+1.
__global__ __launch_bounds__(256, 1)
void gemm_kernel(const float* __restrict__ X, const float* __restrict__ W0,
                 float* __restrict__ G)
{
    __shared__ __align__(16) ushort As[2][16 * 1024];   // 2 x 32 KB bf16

    const int tid  = threadIdx.x;
    const int lane = tid & 63;
    const int wave = tid >> 6;
    const int b    = blockIdx.x & 7;
    const int slot = blockIdx.x >> 3;    // 0..33
    const int nt0  = slot * 2;
    const int t0   = wave * 16;

    const int r  = lane & 15;            // fragment row
    const int kb = lane >> 4;            // k-block 0..3

    // ---- stage mapping: thread (j = tid>>4 row, x = tid&15), 16 chunks ----
    const int j  = tid >> 4;
    const int x  = tid & 15;
    const int sj = (j & 7) << 4;         // XOR swizzle for row j

    const float* __restrict__ Xb = X + (size_t)b * TT * NI;
    const float* __restrict__ Wb = W0 + (size_t)b * NO * NI;
#define SRCROW(nt) ((((nt) * 16) < NO) ? (Wb + ((size_t)((nt) * 16) + j) * NI) \
                                       : (Xb + ((size_t)((nt) * 16 - NO) + j) * NI))

    // ---- issue W panel-0 loads FIRST (cold stream starts at cycle 0) ----
    float4 v[16];
    {
        const float* sr = SRCROW(nt0) + x * 4;
#pragma unroll
        for (int c = 0; c < 16; ++c)
            v[c] = *reinterpret_cast<const float4*>(sr + c * 64);
    }

    // ---- B-frags: f32 X -> in-register cvt (hides under W latency) ----
    bf16x8 breg[32];
    {
        const float* __restrict__ Bb = Xb + (size_t)(t0 + r) * NI + kb * 8;
#pragma unroll
        for (int kk = 0; kk < 32; ++kk) {
            const float4 lo = *reinterpret_cast<const float4*>(Bb + kk * 32);
            const float4 hi = *reinterpret_cast<const float4*>(Bb + kk * 32 + 4);
            bf16x8 f;
            f[0] = f2bf(lo.x); f[1] = f2bf(lo.y); f[2] = f2bf(lo.z); f[3] = f2bf(lo.w);
            f[4] = f2bf(hi.x); f[5] = f2bf(hi.y); f[6] = f2bf(hi.z); f[7] = f2bf(hi.w);
            breg[kk] = f;
        }
    }

    // ---- cvt + swizzled ds_write -> buf 0 ----
#pragma unroll
    for (int c = 0; c < 16; ++c) {
        short4 s4;
        s4.x = f2bf(v[c].x); s4.y = f2bf(v[c].y);
        s4.z = f2bf(v[c].z); s4.w = f2bf(v[c].w);
        char* dst = (char*)As[0] + j * 2048 + c * 128 + ((x * 8) ^ sj);
        *reinterpret_cast<short4*>(dst) = s4;
    }
    __syncthreads();

    // swizzled read bases (verified R13: phys = r*2048 + ((kb^(r&3))<<4)
    //  | (((kk&1)^((r>>2)&1))<<6) + (kk>>1)*128 )
    const int lanebyte = (r << 11) | ((kb ^ (r & 3)) << 4);
    const int rbit = (r >> 2) & 1;

    const int tcol = lane & 15;
    const int mrow = (lane >> 4) * 4;

#pragma unroll
    for (int p = 0; p < 2; ++p) {
        if (p == 0) {
            // issue panel-1 loads now; they fly during panel-0 compute
            const float* sr = SRCROW(nt0 + 1) + x * 4;
#pragma unroll
            for (int c = 0; c < 16; ++c)
                v[c] = *reinterpret_cast<const float4*>(sr + c * 64);
        }

        const char* base = (const char*)As[p] + lanebyte;
        const char* ApE = base + (rbit << 6);
        const char* ApO = base + ((rbit ^ 1) << 6);

        f32x4 acc = {0.f, 0.f, 0.f, 0.f};
#pragma unroll
        for (int kk2 = 0; kk2 < 16; ++kk2) {
            const bf16x8 ae = *reinterpret_cast<const bf16x8*>(ApE + kk2 * 128);
            acc = __builtin_amdgcn_mfma_f32_16x16x32_bf16(ae, breg[2 * kk2], acc, 0, 0, 0);
            const bf16x8 ao = *reinterpret_cast<const bf16x8*>(ApO + kk2 * 128);
            acc = __builtin_amdgcn_mfma_f32_16x16x32_bf16(ao, breg[2 * kk2 + 1], acc, 0, 0, 0);
        }

        // D layout: col t = lane&15, row n = (lane>>4)*4 + rr  [m89-verified]
        const int n0 = (nt0 + p) * 16;
#pragma unroll
        for (int rr = 0; rr < 4; ++rr)
            G[((size_t)b * NTOT + n0 + mrow + rr) * TT + t0 + tcol] = acc[rr];

        if (p == 0) {
            // write-late: cvt + ds_write panel 1 into buf 1, then barrier
#pragma unroll
            for (int c = 0; c < 16; ++c) {
                short4 s4;
                s4.x = f2bf(v[c].x); s4.y = f2bf(v[c].y);
                s4.z = f2bf(v[c].z); s4.w = f2bf(v[c].w);
                char* dst = (char*)As[1] + j * 2048 + c * 128 + ((x * 8) ^ sj);
                *reinterpret_cast<short4*>(dst) = s4;
            }
            __syncthreads();
        }
    }
#undef SRCROW
}

// ---------- Kernel 2: lane-parallel projected-Oja scan (R10/R13) ----------
// 512 blocks x 256 thr (4 waves). Block: batch b = bid&7, 16 o-rows.
__global__ __launch_bounds__(256, 8)
void scan_kernel(const float* __restrict__ G, float* __restrict__ out)
{
    __shared__ float Sl[TT][TT];      // 16 KB: S[b]
    __shared__ float ybuf[16][68];    // row-local y trajectories (padded)

    const int tid  = threadIdx.x;
    const int lane = tid & 63;
    const int wave = tid >> 6;
    const int b  = blockIdx.x & 7;
    const int o0 = (blockIdx.x >> 3) * 16;

    // stage S[b] = G rows 1024..1087 (4096 floats; 4 float4 per thread)
    {
        const float4* __restrict__ src =
            reinterpret_cast<const float4*>(G + ((size_t)b * NTOT + NO) * TT);
        float4* dst = reinterpret_cast<float4*>(&Sl[0][0]);
#pragma unroll
        for (int q = 0; q < 4; ++q)
            dst[tid + q * 256] = src[tid + q * 256];
    }

    const int r  = lane & 3;
    const int jb = lane >> 2;
    const int row = o0 + wave * 4 + r;

    const float4 uu = *reinterpret_cast<const float4*>(
        G + ((size_t)b * NTOT + row) * TT + jb * 4);
    float u0 = uu.x, u1 = uu.y, u2 = uu.z, u3 = uu.w;

    __syncthreads();

    const float lr   = 1.0f / 1024.0f;
    const float nL2E = -1.44269504f;
    float y0 = 0.f, y1 = 0.f, y2 = 0.f, y3 = 0.f;

#pragma unroll
    for (int t = 0; t < TT; ++t) {
        const int srcl = (t & 0x3C) | r;
        const float uv = ((t & 3) == 0) ? u0 : ((t & 3) == 1) ? u1
                       : ((t & 3) == 2) ? u2 : u3;
        const float pre = __shfl(uv, srcl, 64);

        const float e = __builtin_amdgcn_exp2f(pre * nL2E);
        const float y = __builtin_amdgcn_rcpf(1.0f + e);

        const bool own = (jb == (t >> 2));
        if ((t & 3) == 0) y0 = own ? y : y0;
        if ((t & 3) == 1) y1 = own ? y : y1;
        if ((t & 3) == 2) y2 = own ? y : y2;
        if ((t & 3) == 3) y3 = own ? y : y3;

        const float c2 = lr * y;
        const float c1 = fmaf(-c2, y, 1.0f);

        const float4 s = *reinterpret_cast<const float4*>(&Sl[t][jb * 4]);
        u0 = fmaf(c1, u0, c2 * s.x);
        u1 = fmaf(c1, u1, c2 * s.y);
        u2 = fmaf(c1, u2, c2 * s.z);
        u3 = fmaf(c1, u3, c2 * s.w);
    }

    {
        float4 yv; yv.x = y0; yv.y = y1; yv.z = y2; yv.w = y3;
        *reinterpret_cast<float4*>(&ybuf[wave * 4 + r][jb * 4]) = yv;
    }
    __syncthreads();

    {
        const int t = tid >> 2;
        const int g = tid & 3;
        float4 ov;
        ov.x = ybuf[g * 4 + 0][t];
        ov.y = ybuf[g * 4 + 1][t];
        ov.z = ybuf[g * 4 + 2][t];
        ov.w = ybuf[g * 4 + 3][t];
        *reinterpret_cast<float4*>(
            &out[(size_t)b * TT * NO + (size_t)t * NO + o0 + g * 4]) = ov;
    }
}

extern "C" void kernel_launch(void* const* d_in, const int* in_sizes, int n_in,
                              void* d_out, int out_size, void* d_ws, size_t ws_size,
                              hipStream_t stream) {
    const float* X  = (const float*)d_in[0];   // [8][64][1024]
    const float* W0 = (const float*)d_in[1];   // [8][1024][1024]
    float* out = (float*)d_out;                // [8][64][1024]

    float* G = (float*)d_ws;                   // [8][1088][64] f32 = 2,228,224 B

    gemm_kernel<<<34 * BB, 256, 0, stream>>>(X, W0, G);
    scan_kernel<<<512, 256, 0, stream>>>(G, out);
}